// Round 1
// 217.381 us; speedup vs baseline: 1.0392x; 1.0392x over previous
//
#include <hip/hip_runtime.h>
#include <math.h>

// Problem constants
#define B_SZ 2
#define SEQ 2048
#define DMODEL 1024
#define NH 16
#define DK 64
#define NQKV 3072
#define M_ROWS 4096

#define NEG_BIG (-3.0e38f)
#define SCL 0.18033688011112042f   // 0.125 * log2(e)

typedef short short8 __attribute__((ext_vector_type(8)));
typedef float v4f __attribute__((ext_vector_type(4)));
typedef unsigned short ushort_t;

__device__ inline ushort_t f2bf(float f) {
    unsigned u = __float_as_uint(f);
    u += 0x7fffu + ((u >> 16) & 1u);   // RNE
    return (ushort_t)(u >> 16);
}

// packed f32x2 -> bf16x2 (RNE), single VALU op
__device__ __forceinline__ unsigned cvt_pk_bf16(float lo, float hi) {
    unsigned r;
    asm("v_cvt_pk_bf16_f32 %0, %1, %2" : "=v"(r) : "v"(lo), "v"(hi));
    return r;
}
// a' = {a[g0], a[g1], b[g0], b[g1]}, b' = {a[g2], a[g3], b[g2], b[g3]}  (16-lane groups)
__device__ __forceinline__ void permlane32_swap(unsigned &a, unsigned &b) {
    asm("v_permlane32_swap_b32 %0, %1" : "+v"(a), "+v"(b));
}
// a' = {a[g0], b[g0], a[g2], b[g2]}, b' = {a[g1], b[g1], a[g3], b[g3]}
__device__ __forceinline__ void permlane16_swap(unsigned &a, unsigned &b) {
    asm("v_permlane16_swap_b32 %0, %1" : "+v"(a), "+v"(b));
}

// async global(16B/lane) -> LDS (wave-uniform base + lane*16)
__device__ __forceinline__ void gl_lds16(const ushort_t* g, ushort_t* l) {
    __builtin_amdgcn_global_load_lds(
        (const __attribute__((address_space(1))) unsigned int*)g,
        (__attribute__((address_space(3))) unsigned int*)l, 16, 0, 0);
}

// ---------------------------------------------------------------------------
// Kernel 0: fused prep — fp32->bf16 converts (x, Wa, Wo) + RoPE tables.
// ---------------------------------------------------------------------------
__global__ __launch_bounds__(256) void prep_kernel(
    const float* __restrict__ x, const float* __restrict__ Wa,
    const float* __restrict__ Wo, const float* __restrict__ rope,
    ushort_t* __restrict__ xb, ushort_t* __restrict__ Wab, ushort_t* __restrict__ Wob,
    float* __restrict__ cosT, float* __restrict__ sinT)
{
    const int bid = blockIdx.x;
    if (bid < 8192) {
        const float* src; ushort_t* dst; int i;
        if (bid < 4096)      { src = x;  dst = xb;  i = bid * 256 + threadIdx.x; }
        else if (bid < 7168) { src = Wa; dst = Wab; i = (bid - 4096) * 256 + threadIdx.x; }
        else                 { src = Wo; dst = Wob; i = (bid - 7168) * 256 + threadIdx.x; }
        float4 v = reinterpret_cast<const float4*>(src)[i];
        ushort4 r;
        r.x = f2bf(v.x); r.y = f2bf(v.y); r.z = f2bf(v.z); r.w = f2bf(v.w);
        reinterpret_cast<ushort4*>(dst)[i] = r;
    } else {
        const int i = (bid - 8192) * 256 + threadIdx.x;   // [0, 2048*64)
        const int p = i >> 6, d = i & 63;
        const float* Rp = rope + (size_t)p * 4096;
        const float c = Rp[d * 64 + d];
        const float s = Rp[(d | 1) * 64 + (d & ~1)];
        cosT[i] = c;
        sinT[i] = (d & 1) ? s : -s;
    }
}

// ---------------------------------------------------------------------------
// Kernel 1: QKV projection + RoPE -> Q/K bf16 [B,H,S,DK], V DIRECTLY
// transposed -> Vt [B,H,DK,S] (transpose fused into the epilogue).
// BK=64, XOR-swizzled gl_lds staging (verified R10).
// A = Wa (rows e), B = xb (rows s). C/D: col=lm -> s, row=g*4+reg -> e.
// Q is pre-scaled by SCL = 0.125*log2(e) so attention softmax needs no
// per-score multiply (exp2 folding happens entirely in Q).
// ---------------------------------------------------------------------------
#define ES_STRIDE 136
extern __shared__ ushort_t qkv_smem[];

__global__ __launch_bounds__(256) void qkv_mfma_kernel(
    const ushort_t* __restrict__ xb,   // [4096,1024] bf16
    const ushort_t* __restrict__ Wab,  // [3072,1024] bf16
    const float* __restrict__ cosT, const float* __restrict__ sinT,
    const int* __restrict__ tpos,
    ushort_t* __restrict__ Qb, ushort_t* __restrict__ Kb, ushort_t* __restrict__ Vtb)
{
    // staging: A = chunks [0,1024) (128 rows x 8 chunks), B = chunks [1024,2048)
    ushort_t* Es = qkv_smem;           // [128][ES_STRIDE] epilogue tile (aliases)

    const int tid = threadIdx.x;
    const int w = tid >> 6, lane = tid & 63;
    const int lm = lane & 15, g = lane >> 4;
    const int wm = (w >> 1) * 64, wn = (w & 1) * 64;   // wm: e-dim, wn: m-dim
    const int e0 = blockIdx.x * 128, m0 = blockIdx.y * 128;

    // staging decode (once): 8 chunks/thread; j<4 -> A, j>=4 -> B
    int srow[8], skc[8];
#pragma unroll
    for (int j = 0; j < 8; ++j) {
        const int c = tid + 256 * j;          // phys chunk 0..2047
        const int cm = c & 1023;
        const int row = cm >> 3, pp = cm & 7;
        srow[j] = row;
        skc[j] = (pp ^ (row & 7)) * 8;        // logical k offset (ushorts)
    }

    v4f acc[4][4] = {};

    for (int k0 = 0; k0 < DMODEL; k0 += 64) {
        __syncthreads();   // previous iter's frag reads done
#pragma unroll
        for (int j = 0; j < 4; ++j)
            gl_lds16(&Wab[(size_t)(e0 + srow[j]) * DMODEL + k0 + skc[j]],
                     &qkv_smem[(tid + 256 * j) * 8]);
#pragma unroll
        for (int j = 4; j < 8; ++j)
            gl_lds16(&xb [(size_t)(m0 + srow[j]) * DMODEL + k0 + skc[j]],
                     &qkv_smem[(tid + 256 * j) * 8]);
        __syncthreads();   // drains vmcnt -> LDS visible

#pragma unroll
        for (int kb = 0; kb < 2; ++kb) {
            short8 af[4], bfr[4];
#pragma unroll
            for (int mf = 0; mf < 4; ++mf) {
                const int r = wm + mf * 16 + lm;
                af[mf] = *reinterpret_cast<const short8*>(
                    &qkv_smem[(r * 8 + ((kb * 4 + g) ^ (r & 7))) * 8]);
            }
#pragma unroll
            for (int nf = 0; nf < 4; ++nf) {
                const int r = wn + nf * 16 + lm;
                bfr[nf] = *reinterpret_cast<const short8*>(
                    &qkv_smem[8192 + (r * 8 + ((kb * 4 + g) ^ (r & 7))) * 8]);
            }
#pragma unroll
            for (int mf = 0; mf < 4; ++mf)
#pragma unroll
                for (int nf = 0; nf < 4; ++nf)
                    acc[mf][nf] = __builtin_amdgcn_mfma_f32_16x16x32_bf16(af[mf], bfr[nf], acc[mf][nf], 0, 0, 0);
        }
    }

    __syncthreads();   // all frag reads done; Es may alias staging

    const int which = e0 >> 10;            // 0=Q,1=K,2=V (block-uniform)
    const int h0 = (e0 & 1023) >> 6;
    const int bb = m0 >> 11, s0 = m0 & 2047;

    if (which < 2) {
        ushort_t* buf = (which == 0) ? Qb : Kb;
        const float qs = (which == 0) ? SCL : 1.0f;   // fold softmax scale into Q
        // RoPE (in-lane) + write Es[s_loc][e_loc]
#pragma unroll
        for (int mf = 0; mf < 4; ++mf) {
            const int ebase = wm + mf * 16 + g * 4;
            const int d0 = (e0 + ebase) & 63;
#pragma unroll
            for (int nf = 0; nf < 4; ++nf) {
                const int sloc = wn + nf * 16 + lm;
                float v[4] = {acc[mf][nf][0], acc[mf][nf][1], acc[mf][nf][2], acc[mf][nf][3]};
                const int p = tpos[s0 + sloc];
                const float4 c4 = *reinterpret_cast<const float4*>(&cosT[p * 64 + d0]);
                const float4 s4 = *reinterpret_cast<const float4*>(&sinT[p * 64 + d0]);
                const float r0 = (c4.x * v[0] + s4.x * v[1]) * qs;
                const float r1 = (c4.y * v[1] + s4.y * v[0]) * qs;
                const float r2 = (c4.z * v[2] + s4.z * v[3]) * qs;
                const float r3 = (c4.w * v[3] + s4.w * v[2]) * qs;
                uint2 pp;
                pp.x = (unsigned)f2bf(r0) | ((unsigned)f2bf(r1) << 16);
                pp.y = (unsigned)f2bf(r2) | ((unsigned)f2bf(r3) << 16);
                *reinterpret_cast<uint2*>(&Es[sloc * ES_STRIDE + ebase]) = pp;
            }
        }
        __syncthreads();
        // coalesced store of contiguous [s][d] head slabs
#pragma unroll
        for (int hh = 0; hh < 2; ++hh) {
            ushort_t* dst = buf + (((size_t)bb * NH + h0 + hh) * SEQ + s0) * DK;
#pragma unroll
            for (int t = 0; t < 4; ++t) {
                const int o = (t * 256 + tid) * 8;
                const int sloc = o >> 6, d = o & 63;
                const short8 vv = *reinterpret_cast<const short8*>(&Es[sloc * ES_STRIDE + hh * 64 + d]);
                *reinterpret_cast<short8*>(&dst[o]) = vv;
            }
        }
    } else {
        // V: write Es TRANSPOSED [e_loc][s_loc] (stride 136: 128 s + pad),
        // then store contiguous [d][s] slabs to Vtb [B,H,DK,S].
#pragma unroll
        for (int mf = 0; mf < 4; ++mf) {
            const int ebase = wm + mf * 16 + g * 4;
#pragma unroll
            for (int nf = 0; nf < 4; ++nf) {
                const int sloc = wn + nf * 16 + lm;
                Es[(ebase + 0) * ES_STRIDE + sloc] = f2bf(acc[mf][nf][0]);
                Es[(ebase + 1) * ES_STRIDE + sloc] = f2bf(acc[mf][nf][1]);
                Es[(ebase + 2) * ES_STRIDE + sloc] = f2bf(acc[mf][nf][2]);
                Es[(ebase + 3) * ES_STRIDE + sloc] = f2bf(acc[mf][nf][3]);
            }
        }
        __syncthreads();
        // 2048 chunks (2 heads x 64 d x 16 s-chunks), 8 per thread
#pragma unroll
        for (int t = 0; t < 8; ++t) {
            const int c = t * 256 + tid;
            const int hh = c >> 10, cm = c & 1023;
            const int d = cm >> 4, s8c = (cm & 15) * 8;
            const short8 vv = *reinterpret_cast<const short8*>(&Es[(hh * 64 + d) * ES_STRIDE + s8c]);
            ushort_t* dst = Vtb + ((size_t)bb * NH + h0 + hh) * SEQ * DK + (size_t)d * SEQ + s0 + s8c;
            *reinterpret_cast<short8*>(dst) = vv;
        }
    }
}

// ---------------------------------------------------------------------------
// Kernel 2: flash attention — merged q-tiles, fixed-max softmax (exp2 fold,
// scale pre-folded into Q), SINGLE-BARRIER double-buffered K/V LDS staging
// with register prefetch.
// VALU diet vs prior version:
//   - P -> bf16 via v_cvt_pk_bf16_f32 (8 ops replace ~70)
//   - P fragment transpose fully in-register via permlane32/16_swap
//     (Ps LDS buffer deleted; no write->read round trip)
//   - row-sum l via mfma(ones, pf) on the idle matrix pipe (replaces 16
//     f32 adds/step AND the epilogue shfl reduction; denominator now uses
//     the same bf16 P as the numerator)
//   - kf/vf fragment loads hoisted: shared A/B iterations read K/V once
// ---------------------------------------------------------------------------
#define ATTN_STEP(QF0, QF1, QROW, LACC, OACC, DIAG, C0)                           \
    {                                                                             \
        v4f sacc[4] = {};                                                         \
        _Pragma("unroll")                                                         \
        for (int nf = 0; nf < 4; ++nf) {                                          \
            sacc[nf] = __builtin_amdgcn_mfma_f32_16x16x32_bf16(kf[nf][0], QF0, sacc[nf], 0, 0, 0); \
            sacc[nf] = __builtin_amdgcn_mfma_f32_16x16x32_bf16(kf[nf][1], QF1, sacc[nf], 0, 0, 0); \
        }                                                                         \
        if (DIAG) {                                                               \
            _Pragma("unroll")                                                     \
            for (int nf = 0; nf < 4; ++nf)                                        \
                _Pragma("unroll")                                                 \
                for (int reg = 0; reg < 4; ++reg) {                               \
                    const int kv = (C0) + nf * 16 + g * 4 + reg;                  \
                    if (kv > (QROW)) sacc[nf][reg] = NEG_BIG;                     \
                }                                                                 \
        }                                                                         \
        unsigned pk0[8];                                                          \
        _Pragma("unroll")                                                         \
        for (int nf = 0; nf < 4; ++nf) {                                          \
            pk0[nf * 2]     = cvt_pk_bf16(exp2f(sacc[nf][0]), exp2f(sacc[nf][1])); \
            pk0[nf * 2 + 1] = cvt_pk_bf16(exp2f(sacc[nf][2]), exp2f(sacc[nf][3])); \
        }                                                                         \
        _Pragma("unroll")                                                         \
        for (int kc = 0; kc < 2; ++kc) {                                          \
            unsigned x0 = pk0[kc * 4 + 0], y0 = pk0[kc * 4 + 2];                  \
            unsigned x1 = pk0[kc * 4 + 1], y1 = pk0[kc * 4 + 3];                  \
            permlane32_swap(x0, y0); permlane16_swap(x0, y0);                     \
            permlane32_swap(x1, y1); permlane16_swap(x1, y1);                     \
            union { unsigned u[4]; short8 s; } pu;                                \
            pu.u[0] = x0; pu.u[1] = x1; pu.u[2] = y0; pu.u[3] = y1;               \
            const short8 pf = pu.s;                                               \
            LACC = __builtin_amdgcn_mfma_f32_16x16x32_bf16(ones8, pf, LACC, 0, 0, 0); \
            _Pragma("unroll")                                                     \
            for (int df = 0; df < 4; ++df)                                        \
                OACC[df] = __builtin_amdgcn_mfma_f32_16x16x32_bf16(vf[df][kc], pf, OACC[df], 0, 0, 0); \
        }                                                                         \
    }

__global__ __launch_bounds__(256, 2) void attn_mfma_kernel(
    const ushort_t* __restrict__ Qb, const ushort_t* __restrict__ Kb,
    const ushort_t* __restrict__ Vtb, ushort_t* __restrict__ attb)
{
    __shared__ ushort_t Ks[2][64][72];   // [buf][kv][d]
    __shared__ ushort_t Vs[2][64][72];   // [buf][d][kv]  (V^T)

    const int tid = threadIdx.x;
    const int w = tid >> 6, lane = tid & 63;
    const int lm = lane & 15, g = lane >> 4, lk8 = g * 8;

    const int u = blockIdx.x;                     // 0..15
    const int h = blockIdx.y, b = blockIdx.z;
    const size_t ho = ((size_t)b * NH + h) * SEQ * DK;
    const ushort_t* Qh = Qb + ho;
    const ushort_t* Kh = Kb + ho;
    const ushort_t* Vth = Vtb + ho;               // [DK][SEQ]

    const int rr0 = tid >> 3, cc80 = (tid & 7) * 8;
    const int rr1 = (tid + 256) >> 3, cc81 = ((tid + 256) & 7) * 8;

    const int it1 = u, it2 = 31 - u;              // it1 <= it2 (u < 16)
    const int qrowA = it1 * 64 + w * 16 + lm;
    const int qrowB = it2 * 64 + w * 16 + lm;

    const short8 qa0 = *reinterpret_cast<const short8*>(&Qh[(size_t)qrowA * DK + lk8]);
    const short8 qa1 = *reinterpret_cast<const short8*>(&Qh[(size_t)qrowA * DK + 32 + lk8]);
    const short8 qb0 = *reinterpret_cast<const short8*>(&Qh[(size_t)qrowB * DK + lk8]);
    const short8 qb1 = *reinterpret_cast<const short8*>(&Qh[(size_t)qrowB * DK + 32 + lk8]);

    const short8 ones8 = {16256, 16256, 16256, 16256, 16256, 16256, 16256, 16256}; // bf16 1.0

    v4f laccA = {}, laccB = {};
    v4f OA[4] = {}, OB[4] = {};

    // preload jt=0
    short8 kreg[2], vreg[2];
    kreg[0] = *reinterpret_cast<const short8*>(&Kh[(size_t)rr0 * DK + cc80]);
    kreg[1] = *reinterpret_cast<const short8*>(&Kh[(size_t)rr1 * DK + cc81]);
    vreg[0] = *reinterpret_cast<const short8*>(&Vth[(size_t)rr0 * SEQ + cc80]);
    vreg[1] = *reinterpret_cast<const short8*>(&Vth[(size_t)rr1 * SEQ + cc81]);

    for (int jt = 0; jt <= it2; ++jt) {
        const int c0 = jt * 64;
        const int bufi = jt & 1;
        ushort_t (*Ksb)[72] = Ks[bufi];
        ushort_t (*Vsb)[72] = Vs[bufi];

        *reinterpret_cast<short8*>(&Ksb[rr0][cc80]) = kreg[0];
        *reinterpret_cast<short8*>(&Ksb[rr1][cc81]) = kreg[1];
        *reinterpret_cast<short8*>(&Vsb[rr0][cc80]) = vreg[0];
        *reinterpret_cast<short8*>(&Vsb[rr1][cc81]) = vreg[1];

        if (jt < it2) {    // prefetch next tile; latency hides behind compute
            const int c0n = c0 + 64;
            kreg[0] = *reinterpret_cast<const short8*>(&Kh[(size_t)(c0n + rr0) * DK + cc80]);
            kreg[1] = *reinterpret_cast<const short8*>(&Kh[(size_t)(c0n + rr1) * DK + cc81]);
            vreg[0] = *reinterpret_cast<const short8*>(&Vth[(size_t)rr0 * SEQ + c0n + cc80]);
            vreg[1] = *reinterpret_cast<const short8*>(&Vth[(size_t)rr1 * SEQ + c0n + cc81]);
        }

        __syncthreads();   // staged (single barrier per iter; dbuf handles WAR)

        // shared K/V fragment loads (both q-tiles consume the same tile)
        short8 kf[4][2], vf[4][2];
#pragma unroll
        for (int nf = 0; nf < 4; ++nf) {
            kf[nf][0] = *reinterpret_cast<const short8*>(&Ksb[nf * 16 + lm][lk8]);
            kf[nf][1] = *reinterpret_cast<const short8*>(&Ksb[nf * 16 + lm][32 + lk8]);
        }
#pragma unroll
        for (int df = 0; df < 4; ++df) {
            vf[df][0] = *reinterpret_cast<const short8*>(&Vsb[df * 16 + lm][lk8]);
            vf[df][1] = *reinterpret_cast<const short8*>(&Vsb[df * 16 + lm][32 + lk8]);
        }

        // tile B (always active; masks on its own diagonal)
        ATTN_STEP(qb0, qb1, qrowB, laccB, OB, (jt == it2), c0)
        // tile A (active while jt <= it1)
        if (jt <= it1) {
            ATTN_STEP(qa0, qa1, qrowA, laccA, OA, (jt == it1), c0)
        }
    }

    // epilogue: lacc already holds the FULL row sum in every lane (ones-MFMA
    // broadcasts the k-reduction to all 16 C-rows) -> no shuffle needed.
    {
        const float inv = 1.0f / laccA[0];
#pragma unroll
        for (int df = 0; df < 4; ++df) {
            uint2 st;
            st.x = cvt_pk_bf16(OA[df][0] * inv, OA[df][1] * inv);
            st.y = cvt_pk_bf16(OA[df][2] * inv, OA[df][3] * inv);
            *reinterpret_cast<uint2*>(
                &attb[((size_t)b * SEQ + qrowA) * DMODEL + h * DK + df * 16 + g * 4]) = st;
        }
    }
    {
        const float inv = 1.0f / laccB[0];
#pragma unroll
        for (int df = 0; df < 4; ++df) {
            uint2 st;
            st.x = cvt_pk_bf16(OB[df][0] * inv, OB[df][1] * inv);
            st.y = cvt_pk_bf16(OB[df][2] * inv, OB[df][3] * inv);
            *reinterpret_cast<uint2*>(
                &attb[((size_t)b * SEQ + qrowB) * DMODEL + h * DK + df * 16 + g * 4]) = st;
        }
    }
}

// ---------------------------------------------------------------------------
// Kernel 3: output projection — BK=64, XOR-swizzled gl_lds staging.
// ---------------------------------------------------------------------------
__global__ __launch_bounds__(256) void out_mfma_kernel(
    const ushort_t* __restrict__ attb,  // [4096,1024] bf16
    const ushort_t* __restrict__ Wob,   // [1024,1024] bf16
    float* __restrict__ out)            // [4096,1024] fp32
{
    __shared__ ushort_t smem[16384];    // A chunks [0,1024), B [1024,2048)

    const int tid = threadIdx.x;
    const int w = tid >> 6, lane = tid & 63;
    const int lm = lane & 15, g = lane >> 4;
    const int wm = (w >> 1) * 64, wn = (w & 1) * 64;
    const int m0 = blockIdx.y * 128, n0 = blockIdx.x * 128;

    int srow[8], skc[8];
#pragma unroll
    for (int j = 0; j < 8; ++j) {
        const int c = tid + 256 * j;
        const int cm = c & 1023;
        const int row = cm >> 3, pp = cm & 7;
        srow[j] = row;
        skc[j] = (pp ^ (row & 7)) * 8;
    }

    v4f acc[4][4] = {};

    for (int k0 = 0; k0 < DMODEL; k0 += 64) {
        __syncthreads();
#pragma unroll
        for (int j = 0; j < 4; ++j)
            gl_lds16(&attb[(size_t)(m0 + srow[j]) * DMODEL + k0 + skc[j]],
                     &smem[(tid + 256 * j) * 8]);
#pragma unroll
        for (int j = 4; j < 8; ++j)
            gl_lds16(&Wob[(size_t)(n0 + srow[j]) * DMODEL + k0 + skc[j]],
                     &smem[(tid + 256 * j) * 8]);
        __syncthreads();

#pragma unroll
        for (int kb = 0; kb < 2; ++kb) {
            short8 af[4], bfr[4];
#pragma unroll
            for (int mf = 0; mf < 4; ++mf) {
                const int r = wm + mf * 16 + lm;
                af[mf] = *reinterpret_cast<const short8*>(
                    &smem[(r * 8 + ((kb * 4 + g) ^ (r & 7))) * 8]);
            }
#pragma unroll
            for (int nf = 0; nf < 4; ++nf) {
                const int r = wn + nf * 16 + lm;
                bfr[nf] = *reinterpret_cast<const short8*>(
                    &smem[8192 + (r * 8 + ((kb * 4 + g) ^ (r & 7))) * 8]);
            }
#pragma unroll
            for (int mf = 0; mf < 4; ++mf)
#pragma unroll
                for (int nf = 0; nf < 4; ++nf)
                    acc[mf][nf] = __builtin_amdgcn_mfma_f32_16x16x32_bf16(af[mf], bfr[nf], acc[mf][nf], 0, 0, 0);
        }
    }

#pragma unroll
    for (int mf = 0; mf < 4; ++mf)
#pragma unroll
        for (int reg = 0; reg < 4; ++reg) {
            const int m = m0 + wm + mf * 16 + g * 4 + reg;
#pragma unroll
            for (int nf = 0; nf < 4; ++nf) {
                const int n = n0 + wn + nf * 16 + lm;
                out[(size_t)m * DMODEL + n] = acc[mf][nf][reg];
            }
        }
}

// ---------------------------------------------------------------------------
extern "C" void kernel_launch(void* const* d_in, const int* in_sizes, int n_in,
                              void* d_out, int out_size, void* d_ws, size_t ws_size,
                              hipStream_t stream) {
    (void)in_sizes; (void)n_in; (void)out_size; (void)ws_size;

    const float* x    = (const float*)d_in[0];
    const float* Wa   = (const float*)d_in[1];
    const float* Wo   = (const float*)d_in[2];
    const float* rope = (const float*)d_in[3];
    const int*   tp   = (const int*)d_in[4];
    float* out = (float*)d_out;

    char* ws = (char*)d_ws;
    ushort_t* xb   = (ushort_t*)(ws);                       // 8 MB
    ushort_t* Wab  = (ushort_t*)(ws + (8u << 20));          // 6 MB
    ushort_t* Wob  = (ushort_t*)(ws + (14u << 20));         // 2 MB
    float*    cosT = (float*)   (ws + (16u << 20));         // 0.5 MB
    float*    sinT = (float*)   (ws + (16u << 20) + (512u << 10));
    ushort_t* Qb   = (ushort_t*)(ws + (17u << 20));         // 8 MB
    ushort_t* Kb   = (ushort_t*)(ws + (25u << 20));         // 8 MB
    ushort_t* Vtb  = (ushort_t*)(ws + (33u << 20));         // 8 MB
    ushort_t* attb = (ushort_t*)(ws + (41u << 20));         // 8 MB

    dim3 blk(256);
    prep_kernel<<<dim3(8704), blk, 0, stream>>>(x, Wa, Wo, rope, xb, Wab, Wob, cosT, sinT);

    const size_t qkv_lds = 128 * ES_STRIDE * sizeof(ushort_t);  // 34816 B (>= 32768 staging)
    qkv_mfma_kernel<<<dim3(NQKV / 128, M_ROWS / 128), blk, qkv_lds, stream>>>(
        xb, Wab, cosT, sinT, tp, Qb, Kb, Vtb);
    attn_mfma_kernel<<<dim3(16, NH, B_SZ), blk, 0, stream>>>(Qb, Kb, Vtb, attb);
    out_mfma_kernel<<<dim3(DMODEL / 128, M_ROWS / 128), blk, 0, stream>>>(attb, Wob, out);
}

// Round 2
// 207.822 us; speedup vs baseline: 1.0870x; 1.0460x over previous
//
#include <hip/hip_runtime.h>
#include <math.h>

// Problem constants
#define B_SZ 2
#define SEQ 2048
#define DMODEL 1024
#define NH 16
#define DK 64
#define NQKV 3072
#define M_ROWS 4096

#define NEG_BIG (-3.0e38f)
#define SCL 0.18033688011112042f   // 0.125 * log2(e)

typedef short short8 __attribute__((ext_vector_type(8)));
typedef float v4f __attribute__((ext_vector_type(4)));
typedef unsigned short ushort_t;

__device__ inline ushort_t f2bf(float f) {
    unsigned u = __float_as_uint(f);
    u += 0x7fffu + ((u >> 16) & 1u);   // RNE
    return (ushort_t)(u >> 16);
}

// packed f32x2 -> bf16x2 (RNE), single VALU op
__device__ __forceinline__ unsigned cvt_pk_bf16(float lo, float hi) {
    unsigned r;
    asm("v_cvt_pk_bf16_f32 %0, %1, %2" : "=v"(r) : "v"(lo), "v"(hi));
    return r;
}
__device__ __forceinline__ void permlane32_swap(unsigned &a, unsigned &b) {
    asm("v_permlane32_swap_b32 %0, %1" : "+v"(a), "+v"(b));
}
__device__ __forceinline__ void permlane16_swap(unsigned &a, unsigned &b) {
    asm("v_permlane16_swap_b32 %0, %1" : "+v"(a), "+v"(b));
}

// async global(16B/lane) -> LDS (wave-uniform base + lane*16)
__device__ __forceinline__ void gl_lds16(const ushort_t* g, ushort_t* l) {
    __builtin_amdgcn_global_load_lds(
        (const __attribute__((address_space(1))) unsigned int*)g,
        (__attribute__((address_space(3))) unsigned int*)l, 16, 0, 0);
}

// ---------------------------------------------------------------------------
// Kernel 0: fused prep — fp32->bf16 converts (x, Wa, Wo) + RoPE tables.
// ---------------------------------------------------------------------------
__global__ __launch_bounds__(256) void prep_kernel(
    const float* __restrict__ x, const float* __restrict__ Wa,
    const float* __restrict__ Wo, const float* __restrict__ rope,
    ushort_t* __restrict__ xb, ushort_t* __restrict__ Wab, ushort_t* __restrict__ Wob,
    float* __restrict__ cosT, float* __restrict__ sinT)
{
    const int bid = blockIdx.x;
    if (bid < 8192) {
        const float* src; ushort_t* dst; int i;
        if (bid < 4096)      { src = x;  dst = xb;  i = bid * 256 + threadIdx.x; }
        else if (bid < 7168) { src = Wa; dst = Wab; i = (bid - 4096) * 256 + threadIdx.x; }
        else                 { src = Wo; dst = Wob; i = (bid - 7168) * 256 + threadIdx.x; }
        float4 v = reinterpret_cast<const float4*>(src)[i];
        ushort4 r;
        r.x = f2bf(v.x); r.y = f2bf(v.y); r.z = f2bf(v.z); r.w = f2bf(v.w);
        reinterpret_cast<ushort4*>(dst)[i] = r;
    } else {
        const int i = (bid - 8192) * 256 + threadIdx.x;   // [0, 2048*64)
        const int p = i >> 6, d = i & 63;
        const float* Rp = rope + (size_t)p * 4096;
        const float c = Rp[d * 64 + d];
        const float s = Rp[(d | 1) * 64 + (d & ~1)];
        cosT[i] = c;
        sinT[i] = (d & 1) ? s : -s;
    }
}

// ---------------------------------------------------------------------------
// Kernel 1: QKV projection + RoPE. GEMM core: BK=64, XOR-swizzled gl_lds
// staging, now DOUBLE-BUFFERED with counted vmcnt(8) — next tile's 8 loads
// stay in flight across the barrier (T3/T4), raw s_barrier (no compiler
// vmcnt(0) drain), setprio(1) around the MFMA cluster (T5), bijective
// XCD-chunked block swizzle (T1).
// Q is pre-scaled by SCL = 0.125*log2(e).
// ---------------------------------------------------------------------------
#define ES_STRIDE 136

#define QKV_STAGE(bofs, k0s)                                                   \
    _Pragma("unroll")                                                          \
    for (int j = 0; j < 4; ++j)                                                \
        gl_lds16(&Wab[(size_t)(e0 + srow[j]) * DMODEL + (k0s) + skc[j]],       \
                 &qkv_smem[(bofs) + (tid + 256 * j) * 8]);                     \
    _Pragma("unroll")                                                          \
    for (int j = 4; j < 8; ++j)                                                \
        gl_lds16(&xb[(size_t)(m0 + srow[j]) * DMODEL + (k0s) + skc[j]],        \
                 &qkv_smem[(bofs) + (tid + 256 * j) * 8]);

__global__ __launch_bounds__(256) void qkv_mfma_kernel(
    const ushort_t* __restrict__ xb,   // [4096,1024] bf16
    const ushort_t* __restrict__ Wab,  // [3072,1024] bf16
    const float* __restrict__ cosT, const float* __restrict__ sinT,
    const int* __restrict__ tpos,
    ushort_t* __restrict__ Qb, ushort_t* __restrict__ Kb, ushort_t* __restrict__ Vtb)
{
    // 2 staging buffers x 32KB (A chunks [0,1024), B [1024,2048) each);
    // epilogue tile Es aliases the front.
    __shared__ ushort_t qkv_smem[32768];   // 64 KB
    ushort_t* Es = qkv_smem;               // [128][ES_STRIDE]

    const int tid = threadIdx.x;
    const int w = tid >> 6, lane = tid & 63;
    const int lm = lane & 15, g = lane >> 4;
    const int wm = (w >> 1) * 64, wn = (w & 1) * 64;   // wm: e-dim, wn: m-dim

    // T1: bijective XCD-chunked swizzle (768 = 8 * 96)
    const int lid = blockIdx.y * 24 + blockIdx.x;
    const int swz = (lid & 7) * 96 + (lid >> 3);
    const int e0 = (swz % 24) * 128, m0 = (swz / 24) * 128;

    // staging decode (once): 8 chunks/thread; j<4 -> A, j>=4 -> B
    int srow[8], skc[8];
#pragma unroll
    for (int j = 0; j < 8; ++j) {
        const int c = tid + 256 * j;          // phys chunk 0..2047
        const int cm = c & 1023;
        const int row = cm >> 3, pp = cm & 7;
        srow[j] = row;
        skc[j] = (pp ^ (row & 7)) * 8;        // logical k offset (ushorts)
    }

    v4f acc[4][4] = {};

    QKV_STAGE(0, 0);                          // prologue: tile 0 -> buf0

    for (int t = 0; t < 16; ++t) {
        const int bofs = (t & 1) << 14;       // 0 / 16384 ushorts
        if (t < 15) {
            const int nofs = ((t + 1) & 1) << 14;
            QKV_STAGE(nofs, (t + 1) * 64);    // prefetch next tile (stays in flight)
            __builtin_amdgcn_sched_barrier(0);
            asm volatile("s_waitcnt vmcnt(8)" ::: "memory");   // wait cur's 8 only
        } else {
            __builtin_amdgcn_sched_barrier(0);
            asm volatile("s_waitcnt vmcnt(0)" ::: "memory");
        }
        __builtin_amdgcn_s_barrier();         // cur tile visible to all waves
        __builtin_amdgcn_sched_barrier(0);

        __builtin_amdgcn_s_setprio(1);
#pragma unroll
        for (int kb = 0; kb < 2; ++kb) {
            short8 af[4], bfr[4];
#pragma unroll
            for (int mf = 0; mf < 4; ++mf) {
                const int r = wm + mf * 16 + lm;
                af[mf] = *reinterpret_cast<const short8*>(
                    &qkv_smem[bofs + (r * 8 + ((kb * 4 + g) ^ (r & 7))) * 8]);
            }
#pragma unroll
            for (int nf = 0; nf < 4; ++nf) {
                const int r = wn + nf * 16 + lm;
                bfr[nf] = *reinterpret_cast<const short8*>(
                    &qkv_smem[bofs + 8192 + (r * 8 + ((kb * 4 + g) ^ (r & 7))) * 8]);
            }
#pragma unroll
            for (int mf = 0; mf < 4; ++mf)
#pragma unroll
                for (int nf = 0; nf < 4; ++nf)
                    acc[mf][nf] = __builtin_amdgcn_mfma_f32_16x16x32_bf16(af[mf], bfr[nf], acc[mf][nf], 0, 0, 0);
        }
        __builtin_amdgcn_s_setprio(0);

        __builtin_amdgcn_sched_barrier(0);
        __builtin_amdgcn_s_barrier();         // reads of buf[cur] done before overwrite
        __builtin_amdgcn_sched_barrier(0);
    }

    __syncthreads();   // full fence; Es aliases staging

    const int which = e0 >> 10;            // 0=Q,1=K,2=V (block-uniform)
    const int h0 = (e0 & 1023) >> 6;
    const int bb = m0 >> 11, s0 = m0 & 2047;

    if (which < 2) {
        ushort_t* buf = (which == 0) ? Qb : Kb;
        const float qs = (which == 0) ? SCL : 1.0f;   // fold softmax scale into Q
        // RoPE (in-lane) + write Es[s_loc][e_loc]
#pragma unroll
        for (int mf = 0; mf < 4; ++mf) {
            const int ebase = wm + mf * 16 + g * 4;
            const int d0 = (e0 + ebase) & 63;
#pragma unroll
            for (int nf = 0; nf < 4; ++nf) {
                const int sloc = wn + nf * 16 + lm;
                float v[4] = {acc[mf][nf][0], acc[mf][nf][1], acc[mf][nf][2], acc[mf][nf][3]};
                const int p = tpos[s0 + sloc];
                const float4 c4 = *reinterpret_cast<const float4*>(&cosT[p * 64 + d0]);
                const float4 s4 = *reinterpret_cast<const float4*>(&sinT[p * 64 + d0]);
                const float r0 = (c4.x * v[0] + s4.x * v[1]) * qs;
                const float r1 = (c4.y * v[1] + s4.y * v[0]) * qs;
                const float r2 = (c4.z * v[2] + s4.z * v[3]) * qs;
                const float r3 = (c4.w * v[3] + s4.w * v[2]) * qs;
                uint2 pp;
                pp.x = (unsigned)f2bf(r0) | ((unsigned)f2bf(r1) << 16);
                pp.y = (unsigned)f2bf(r2) | ((unsigned)f2bf(r3) << 16);
                *reinterpret_cast<uint2*>(&Es[sloc * ES_STRIDE + ebase]) = pp;
            }
        }
        __syncthreads();
        // coalesced store of contiguous [s][d] head slabs
#pragma unroll
        for (int hh = 0; hh < 2; ++hh) {
            ushort_t* dst = buf + (((size_t)bb * NH + h0 + hh) * SEQ + s0) * DK;
#pragma unroll
            for (int t = 0; t < 4; ++t) {
                const int o = (t * 256 + tid) * 8;
                const int sloc = o >> 6, d = o & 63;
                const short8 vv = *reinterpret_cast<const short8*>(&Es[sloc * ES_STRIDE + hh * 64 + d]);
                *reinterpret_cast<short8*>(&dst[o]) = vv;
            }
        }
    } else {
        // V: write Es TRANSPOSED [e_loc][s_loc], store [d][s] slabs to Vtb.
#pragma unroll
        for (int mf = 0; mf < 4; ++mf) {
            const int ebase = wm + mf * 16 + g * 4;
#pragma unroll
            for (int nf = 0; nf < 4; ++nf) {
                const int sloc = wn + nf * 16 + lm;
                Es[(ebase + 0) * ES_STRIDE + sloc] = f2bf(acc[mf][nf][0]);
                Es[(ebase + 1) * ES_STRIDE + sloc] = f2bf(acc[mf][nf][1]);
                Es[(ebase + 2) * ES_STRIDE + sloc] = f2bf(acc[mf][nf][2]);
                Es[(ebase + 3) * ES_STRIDE + sloc] = f2bf(acc[mf][nf][3]);
            }
        }
        __syncthreads();
        // 2048 chunks (2 heads x 64 d x 16 s-chunks), 8 per thread
#pragma unroll
        for (int t = 0; t < 8; ++t) {
            const int c = t * 256 + tid;
            const int hh = c >> 10, cm = c & 1023;
            const int d = cm >> 4, s8c = (cm & 15) * 8;
            const short8 vv = *reinterpret_cast<const short8*>(&Es[(hh * 64 + d) * ES_STRIDE + s8c]);
            ushort_t* dst = Vtb + ((size_t)bb * NH + h0 + hh) * SEQ * DK + (size_t)d * SEQ + s0 + s8c;
            *reinterpret_cast<short8*>(dst) = vv;
        }
    }
}

// ---------------------------------------------------------------------------
// Kernel 2: flash attention — merged q-tiles, fixed-max softmax (exp2 fold,
// scale pre-folded into Q), in-register P transpose (cvt_pk + permlane),
// row-sum via ones-MFMA, single-barrier double-buffered K/V staging.
// (unchanged from previous round — verified)
// ---------------------------------------------------------------------------
#define ATTN_STEP(QF0, QF1, QROW, LACC, OACC, DIAG, C0)                           \
    {                                                                             \
        v4f sacc[4] = {};                                                         \
        _Pragma("unroll")                                                         \
        for (int nf = 0; nf < 4; ++nf) {                                          \
            sacc[nf] = __builtin_amdgcn_mfma_f32_16x16x32_bf16(kf[nf][0], QF0, sacc[nf], 0, 0, 0); \
            sacc[nf] = __builtin_amdgcn_mfma_f32_16x16x32_bf16(kf[nf][1], QF1, sacc[nf], 0, 0, 0); \
        }                                                                         \
        if (DIAG) {                                                               \
            _Pragma("unroll")                                                     \
            for (int nf = 0; nf < 4; ++nf)                                        \
                _Pragma("unroll")                                                 \
                for (int reg = 0; reg < 4; ++reg) {                               \
                    const int kv = (C0) + nf * 16 + g * 4 + reg;                  \
                    if (kv > (QROW)) sacc[nf][reg] = NEG_BIG;                     \
                }                                                                 \
        }                                                                         \
        unsigned pk0[8];                                                          \
        _Pragma("unroll")                                                         \
        for (int nf = 0; nf < 4; ++nf) {                                          \
            pk0[nf * 2]     = cvt_pk_bf16(exp2f(sacc[nf][0]), exp2f(sacc[nf][1])); \
            pk0[nf * 2 + 1] = cvt_pk_bf16(exp2f(sacc[nf][2]), exp2f(sacc[nf][3])); \
        }                                                                         \
        _Pragma("unroll")                                                         \
        for (int kc = 0; kc < 2; ++kc) {                                          \
            unsigned x0 = pk0[kc * 4 + 0], y0 = pk0[kc * 4 + 2];                  \
            unsigned x1 = pk0[kc * 4 + 1], y1 = pk0[kc * 4 + 3];                  \
            permlane32_swap(x0, y0); permlane16_swap(x0, y0);                     \
            permlane32_swap(x1, y1); permlane16_swap(x1, y1);                     \
            union { unsigned u[4]; short8 s; } pu;                                \
            pu.u[0] = x0; pu.u[1] = x1; pu.u[2] = y0; pu.u[3] = y1;               \
            const short8 pf = pu.s;                                               \
            LACC = __builtin_amdgcn_mfma_f32_16x16x32_bf16(ones8, pf, LACC, 0, 0, 0); \
            _Pragma("unroll")                                                     \
            for (int df = 0; df < 4; ++df)                                        \
                OACC[df] = __builtin_amdgcn_mfma_f32_16x16x32_bf16(vf[df][kc], pf, OACC[df], 0, 0, 0); \
        }                                                                         \
    }

__global__ __launch_bounds__(256, 2) void attn_mfma_kernel(
    const ushort_t* __restrict__ Qb, const ushort_t* __restrict__ Kb,
    const ushort_t* __restrict__ Vtb, ushort_t* __restrict__ attb)
{
    __shared__ ushort_t Ks[2][64][72];   // [buf][kv][d]
    __shared__ ushort_t Vs[2][64][72];   // [buf][d][kv]  (V^T)

    const int tid = threadIdx.x;
    const int w = tid >> 6, lane = tid & 63;
    const int lm = lane & 15, g = lane >> 4, lk8 = g * 8;

    const int u = blockIdx.x;                     // 0..15
    const int h = blockIdx.y, b = blockIdx.z;
    const size_t ho = ((size_t)b * NH + h) * SEQ * DK;
    const ushort_t* Qh = Qb + ho;
    const ushort_t* Kh = Kb + ho;
    const ushort_t* Vth = Vtb + ho;               // [DK][SEQ]

    const int rr0 = tid >> 3, cc80 = (tid & 7) * 8;
    const int rr1 = (tid + 256) >> 3, cc81 = ((tid + 256) & 7) * 8;

    const int it1 = u, it2 = 31 - u;              // it1 <= it2 (u < 16)
    const int qrowA = it1 * 64 + w * 16 + lm;
    const int qrowB = it2 * 64 + w * 16 + lm;

    const short8 qa0 = *reinterpret_cast<const short8*>(&Qh[(size_t)qrowA * DK + lk8]);
    const short8 qa1 = *reinterpret_cast<const short8*>(&Qh[(size_t)qrowA * DK + 32 + lk8]);
    const short8 qb0 = *reinterpret_cast<const short8*>(&Qh[(size_t)qrowB * DK + lk8]);
    const short8 qb1 = *reinterpret_cast<const short8*>(&Qh[(size_t)qrowB * DK + 32 + lk8]);

    const short8 ones8 = {16256, 16256, 16256, 16256, 16256, 16256, 16256, 16256}; // bf16 1.0

    v4f laccA = {}, laccB = {};
    v4f OA[4] = {}, OB[4] = {};

    // preload jt=0
    short8 kreg[2], vreg[2];
    kreg[0] = *reinterpret_cast<const short8*>(&Kh[(size_t)rr0 * DK + cc80]);
    kreg[1] = *reinterpret_cast<const short8*>(&Kh[(size_t)rr1 * DK + cc81]);
    vreg[0] = *reinterpret_cast<const short8*>(&Vth[(size_t)rr0 * SEQ + cc80]);
    vreg[1] = *reinterpret_cast<const short8*>(&Vth[(size_t)rr1 * SEQ + cc81]);

    for (int jt = 0; jt <= it2; ++jt) {
        const int c0 = jt * 64;
        const int bufi = jt & 1;
        ushort_t (*Ksb)[72] = Ks[bufi];
        ushort_t (*Vsb)[72] = Vs[bufi];

        *reinterpret_cast<short8*>(&Ksb[rr0][cc80]) = kreg[0];
        *reinterpret_cast<short8*>(&Ksb[rr1][cc81]) = kreg[1];
        *reinterpret_cast<short8*>(&Vsb[rr0][cc80]) = vreg[0];
        *reinterpret_cast<short8*>(&Vsb[rr1][cc81]) = vreg[1];

        if (jt < it2) {    // prefetch next tile; latency hides behind compute
            const int c0n = c0 + 64;
            kreg[0] = *reinterpret_cast<const short8*>(&Kh[(size_t)(c0n + rr0) * DK + cc80]);
            kreg[1] = *reinterpret_cast<const short8*>(&Kh[(size_t)(c0n + rr1) * DK + cc81]);
            vreg[0] = *reinterpret_cast<const short8*>(&Vth[(size_t)rr0 * SEQ + c0n + cc80]);
            vreg[1] = *reinterpret_cast<const short8*>(&Vth[(size_t)rr1 * SEQ + c0n + cc81]);
        }

        __syncthreads();   // staged (single barrier per iter; dbuf handles WAR)

        // shared K/V fragment loads (both q-tiles consume the same tile)
        short8 kf[4][2], vf[4][2];
#pragma unroll
        for (int nf = 0; nf < 4; ++nf) {
            kf[nf][0] = *reinterpret_cast<const short8*>(&Ksb[nf * 16 + lm][lk8]);
            kf[nf][1] = *reinterpret_cast<const short8*>(&Ksb[nf * 16 + lm][32 + lk8]);
        }
#pragma unroll
        for (int df = 0; df < 4; ++df) {
            vf[df][0] = *reinterpret_cast<const short8*>(&Vsb[df * 16 + lm][lk8]);
            vf[df][1] = *reinterpret_cast<const short8*>(&Vsb[df * 16 + lm][32 + lk8]);
        }

        // tile B (always active; masks on its own diagonal)
        ATTN_STEP(qb0, qb1, qrowB, laccB, OB, (jt == it2), c0)
        // tile A (active while jt <= it1)
        if (jt <= it1) {
            ATTN_STEP(qa0, qa1, qrowA, laccA, OA, (jt == it1), c0)
        }
    }

    // epilogue: lacc holds the FULL row sum in every lane (ones-MFMA
    // broadcasts the k-reduction to all 16 C-rows) -> no shuffle needed.
    {
        const float inv = 1.0f / laccA[0];
#pragma unroll
        for (int df = 0; df < 4; ++df) {
            uint2 st;
            st.x = cvt_pk_bf16(OA[df][0] * inv, OA[df][1] * inv);
            st.y = cvt_pk_bf16(OA[df][2] * inv, OA[df][3] * inv);
            *reinterpret_cast<uint2*>(
                &attb[((size_t)b * SEQ + qrowA) * DMODEL + h * DK + df * 16 + g * 4]) = st;
        }
    }
    {
        const float inv = 1.0f / laccB[0];
#pragma unroll
        for (int df = 0; df < 4; ++df) {
            uint2 st;
            st.x = cvt_pk_bf16(OB[df][0] * inv, OB[df][1] * inv);
            st.y = cvt_pk_bf16(OB[df][2] * inv, OB[df][3] * inv);
            *reinterpret_cast<uint2*>(
                &attb[((size_t)b * SEQ + qrowB) * DMODEL + h * DK + df * 16 + g * 4]) = st;
        }
    }
}

// ---------------------------------------------------------------------------
// Kernel 3: output projection — same dbuf counted-vmcnt structure as qkv.
// ---------------------------------------------------------------------------
#define OUT_STAGE(bofs, k0s)                                                   \
    _Pragma("unroll")                                                          \
    for (int j = 0; j < 4; ++j)                                                \
        gl_lds16(&attb[(size_t)(m0 + srow[j]) * DMODEL + (k0s) + skc[j]],      \
                 &smem[(bofs) + (tid + 256 * j) * 8]);                         \
    _Pragma("unroll")                                                          \
    for (int j = 4; j < 8; ++j)                                                \
        gl_lds16(&Wob[(size_t)(n0 + srow[j]) * DMODEL + (k0s) + skc[j]],       \
                 &smem[(bofs) + (tid + 256 * j) * 8]);

__global__ __launch_bounds__(256) void out_mfma_kernel(
    const ushort_t* __restrict__ attb,  // [4096,1024] bf16
    const ushort_t* __restrict__ Wob,   // [1024,1024] bf16
    float* __restrict__ out)            // [4096,1024] fp32
{
    __shared__ ushort_t smem[32768];    // 2 x 32KB staging buffers

    const int tid = threadIdx.x;
    const int w = tid >> 6, lane = tid & 63;
    const int lm = lane & 15, g = lane >> 4;
    const int wm = (w >> 1) * 64, wn = (w & 1) * 64;

    // T1: bijective XCD-chunked swizzle (256 = 8 * 32)
    const int lid = blockIdx.y * 8 + blockIdx.x;
    const int swz = (lid & 7) * 32 + (lid >> 3);
    const int m0 = (swz >> 3) * 128, n0 = (swz & 7) * 128;

    int srow[8], skc[8];
#pragma unroll
    for (int j = 0; j < 8; ++j) {
        const int c = tid + 256 * j;
        const int cm = c & 1023;
        const int row = cm >> 3, pp = cm & 7;
        srow[j] = row;
        skc[j] = (pp ^ (row & 7)) * 8;
    }

    v4f acc[4][4] = {};

    OUT_STAGE(0, 0);

    for (int t = 0; t < 16; ++t) {
        const int bofs = (t & 1) << 14;
        if (t < 15) {
            const int nofs = ((t + 1) & 1) << 14;
            OUT_STAGE(nofs, (t + 1) * 64);
            __builtin_amdgcn_sched_barrier(0);
            asm volatile("s_waitcnt vmcnt(8)" ::: "memory");
        } else {
            __builtin_amdgcn_sched_barrier(0);
            asm volatile("s_waitcnt vmcnt(0)" ::: "memory");
        }
        __builtin_amdgcn_s_barrier();
        __builtin_amdgcn_sched_barrier(0);

        __builtin_amdgcn_s_setprio(1);
#pragma unroll
        for (int kb = 0; kb < 2; ++kb) {
            short8 af[4], bfr[4];
#pragma unroll
            for (int mf = 0; mf < 4; ++mf) {
                const int r = wm + mf * 16 + lm;
                af[mf] = *reinterpret_cast<const short8*>(
                    &smem[bofs + (r * 8 + ((kb * 4 + g) ^ (r & 7))) * 8]);
            }
#pragma unroll
            for (int nf = 0; nf < 4; ++nf) {
                const int r = wn + nf * 16 + lm;
                bfr[nf] = *reinterpret_cast<const short8*>(
                    &smem[bofs + 8192 + (r * 8 + ((kb * 4 + g) ^ (r & 7))) * 8]);
            }
#pragma unroll
            for (int mf = 0; mf < 4; ++mf)
#pragma unroll
                for (int nf = 0; nf < 4; ++nf)
                    acc[mf][nf] = __builtin_amdgcn_mfma_f32_16x16x32_bf16(af[mf], bfr[nf], acc[mf][nf], 0, 0, 0);
        }
        __builtin_amdgcn_s_setprio(0);

        __builtin_amdgcn_sched_barrier(0);
        __builtin_amdgcn_s_barrier();
        __builtin_amdgcn_sched_barrier(0);
    }

#pragma unroll
    for (int mf = 0; mf < 4; ++mf)
#pragma unroll
        for (int reg = 0; reg < 4; ++reg) {
            const int m = m0 + wm + mf * 16 + g * 4 + reg;
#pragma unroll
            for (int nf = 0; nf < 4; ++nf) {
                const int n = n0 + wn + nf * 16 + lm;
                out[(size_t)m * DMODEL + n] = acc[mf][nf][reg];
            }
        }
}

// ---------------------------------------------------------------------------
extern "C" void kernel_launch(void* const* d_in, const int* in_sizes, int n_in,
                              void* d_out, int out_size, void* d_ws, size_t ws_size,
                              hipStream_t stream) {
    (void)in_sizes; (void)n_in; (void)out_size; (void)ws_size;

    const float* x    = (const float*)d_in[0];
    const float* Wa   = (const float*)d_in[1];
    const float* Wo   = (const float*)d_in[2];
    const float* rope = (const float*)d_in[3];
    const int*   tp   = (const int*)d_in[4];
    float* out = (float*)d_out;

    char* ws = (char*)d_ws;
    ushort_t* xb   = (ushort_t*)(ws);                       // 8 MB
    ushort_t* Wab  = (ushort_t*)(ws + (8u << 20));          // 6 MB
    ushort_t* Wob  = (ushort_t*)(ws + (14u << 20));         // 2 MB
    float*    cosT = (float*)   (ws + (16u << 20));         // 0.5 MB
    float*    sinT = (float*)   (ws + (16u << 20) + (512u << 10));
    ushort_t* Qb   = (ushort_t*)(ws + (17u << 20));         // 8 MB
    ushort_t* Kb   = (ushort_t*)(ws + (25u << 20));         // 8 MB
    ushort_t* Vtb  = (ushort_t*)(ws + (33u << 20));         // 8 MB
    ushort_t* attb = (ushort_t*)(ws + (41u << 20));         // 8 MB

    dim3 blk(256);
    prep_kernel<<<dim3(8704), blk, 0, stream>>>(x, Wa, Wo, rope, xb, Wab, Wob, cosT, sinT);

    qkv_mfma_kernel<<<dim3(NQKV / 128, M_ROWS / 128), blk, 0, stream>>>(
        xb, Wab, cosT, sinT, tp, Qb, Kb, Vtb);
    attn_mfma_kernel<<<dim3(16, NH, B_SZ), blk, 0, stream>>>(Qb, Kb, Vtb, attb);
    out_mfma_kernel<<<dim3(DMODEL / 128, M_ROWS / 128), blk, 0, stream>>>(attb, Wob, out);
}

// Round 3
// 203.934 us; speedup vs baseline: 1.1077x; 1.0191x over previous
//
#include <hip/hip_runtime.h>
#include <math.h>

// Problem constants
#define B_SZ 2
#define SEQ 2048
#define DMODEL 1024
#define NH 16
#define DK 64
#define NQKV 3072
#define M_ROWS 4096

#define NEG_BIG (-3.0e38f)
#define SCL 0.18033688011112042f   // 0.125 * log2(e)

typedef short short8 __attribute__((ext_vector_type(8)));
typedef float v4f __attribute__((ext_vector_type(4)));
typedef unsigned short ushort_t;

__device__ inline ushort_t f2bf(float f) {
    unsigned u = __float_as_uint(f);
    u += 0x7fffu + ((u >> 16) & 1u);   // RNE
    return (ushort_t)(u >> 16);
}

// packed f32x2 -> bf16x2 (RNE), single VALU op
__device__ __forceinline__ unsigned cvt_pk_bf16(float lo, float hi) {
    unsigned r;
    asm("v_cvt_pk_bf16_f32 %0, %1, %2" : "=v"(r) : "v"(lo), "v"(hi));
    return r;
}
__device__ __forceinline__ void permlane32_swap(unsigned &a, unsigned &b) {
    asm("v_permlane32_swap_b32 %0, %1" : "+v"(a), "+v"(b));
}
__device__ __forceinline__ void permlane16_swap(unsigned &a, unsigned &b) {
    asm("v_permlane16_swap_b32 %0, %1" : "+v"(a), "+v"(b));
}

// async global(16B/lane) -> LDS (wave-uniform base + lane*16)
__device__ __forceinline__ void gl_lds16(const ushort_t* g, ushort_t* l) {
    __builtin_amdgcn_global_load_lds(
        (const __attribute__((address_space(1))) unsigned int*)g,
        (__attribute__((address_space(3))) unsigned int*)l, 16, 0, 0);
}

// ---------------------------------------------------------------------------
// Kernel 0: fused prep — fp32->bf16 converts (x, Wa, Wo) + RoPE tables.
// ---------------------------------------------------------------------------
__global__ __launch_bounds__(256) void prep_kernel(
    const float* __restrict__ x, const float* __restrict__ Wa,
    const float* __restrict__ Wo, const float* __restrict__ rope,
    ushort_t* __restrict__ xb, ushort_t* __restrict__ Wab, ushort_t* __restrict__ Wob,
    float* __restrict__ cosT, float* __restrict__ sinT)
{
    const int bid = blockIdx.x;
    if (bid < 8192) {
        const float* src; ushort_t* dst; int i;
        if (bid < 4096)      { src = x;  dst = xb;  i = bid * 256 + threadIdx.x; }
        else if (bid < 7168) { src = Wa; dst = Wab; i = (bid - 4096) * 256 + threadIdx.x; }
        else                 { src = Wo; dst = Wob; i = (bid - 7168) * 256 + threadIdx.x; }
        float4 v = reinterpret_cast<const float4*>(src)[i];
        ushort4 r;
        r.x = f2bf(v.x); r.y = f2bf(v.y); r.z = f2bf(v.z); r.w = f2bf(v.w);
        reinterpret_cast<ushort4*>(dst)[i] = r;
    } else {
        const int i = (bid - 8192) * 256 + threadIdx.x;   // [0, 2048*64)
        const int p = i >> 6, d = i & 63;
        const float* Rp = rope + (size_t)p * 4096;
        const float c = Rp[d * 64 + d];
        const float s = Rp[(d | 1) * 64 + (d & ~1)];
        cosT[i] = c;
        sinT[i] = (d & 1) ? s : -s;
    }
}

// ---------------------------------------------------------------------------
// Kernel 1: QKV projection + RoPE — 256x256 tile, 8 waves (2e x 4s), BK=64,
// 4-phase-per-K-tile pipelined schedule with per-phase counted vmcnt(6).
//
// LDS (128 KB): dbuf[2] x { A-slab0, A-slab1, B-slab0, B-slab1 }, slab =
// 16 KB = 128 rows x 64 k bf16, XOR-swizzled k-chunks. Slabs interleave rows
// so quadrant (eh,sh) of EVERY wave reads exactly slab A_eh + B_sh:
//   A-slab h holds global e-rows with bit6==h:  r' = ((gr>>7)<<6)|(gr&63)
//   B-slab h holds global s-rows with bit5==h:  r' = ((gs>>6)<<5)|(gs&31)
//
// Phase p of K-tile t (quadrant snake (0,0),(1,0),(1,1),(0,1)):
//   [stage half korder[p]={A0,B0,A1,B1} of tile t+1]  (2 gl_lds/thread)
//   [vmcnt(6)]  -> with 8 loads in flight, retires EXACTLY the half this
//                  phase's MFMA needs (in-order vmcnt retirement)
//   [s_barrier] -> all waves' portions landed
//   [ds_read quadrant operands (12/8/4/0; regs reused on revisit)]
//   [setprio(1); 16 MFMA; setprio(0)]
//   [s_barrier] -> MFMA LDS-reads done before next phase's stage-issue (WAR)
// Tail (t=15): vmcnt 4 -> 2 -> 0.
// Q pre-scaled by SCL = 0.125*log2(e).
// ---------------------------------------------------------------------------
__global__ __launch_bounds__(512, 2) void qkv_mfma_kernel(
    const ushort_t* __restrict__ xb,   // [4096,1024] bf16
    const ushort_t* __restrict__ Wab,  // [3072,1024] bf16
    const float* __restrict__ cosT, const float* __restrict__ sinT,
    const int* __restrict__ tpos,
    ushort_t* __restrict__ Qb, ushort_t* __restrict__ Kb, ushort_t* __restrict__ Vtb)
{
    __shared__ ushort_t qkv_smem[65536];   // 128 KB; epilogue Es aliases
    ushort_t* Es = qkv_smem;

    const int tid = threadIdx.x;
    const int wid = tid >> 6, lane = tid & 63;
    const int lm = lane & 15, g = lane >> 4;
    const int wr = wid >> 2, wc = wid & 3;   // wave: e-half(128), s-quarter(64)

    // XCD-chunked bijective swizzle (192 = 8*24)
    const int lid = blockIdx.y * 12 + blockIdx.x;
    const int swz = (lid & 7) * 24 + (lid >> 3);
    const int e0 = (swz % 12) * 256, m0 = (swz / 12) * 256;

    // staging decode (per thread, once): 2 chunks/half-tile
    int koff[2], partsA[2], partsB[2];
#pragma unroll
    for (int j = 0; j < 2; ++j) {
        const int c = tid + 512 * j;          // phys chunk 0..1023
        const int rA = c >> 3, pp = c & 7;
        koff[j] = (pp ^ (rA & 7)) * 8;
        partsA[j] = ((rA >> 6) << 7) + (rA & 63);   // + h*64 => global e-row
        partsB[j] = ((rA >> 5) << 6) + (rA & 31);   // + h*32 => global s-row
    }

    // stage half-tile `kind` (0=A0,1=A1,2=B0,3=B1) of K-tile t
    auto stage = [&](int t, int kind) {
        const int base = ((t & 1) << 15) + (kind << 13);
        const int k0 = t << 6;
        if (kind < 2) {
#pragma unroll
            for (int j = 0; j < 2; ++j)
                gl_lds16(&Wab[(size_t)(e0 + partsA[j] + kind * 64) * DMODEL + k0 + koff[j]],
                         &qkv_smem[base + (tid + 512 * j) * 8]);
        } else {
#pragma unroll
            for (int j = 0; j < 2; ++j)
                gl_lds16(&xb[(size_t)(m0 + partsB[j] + (kind - 2) * 32) * DMODEL + k0 + koff[j]],
                         &qkv_smem[base + (tid + 512 * j) * 8]);
        }
    };

    v4f acc[8][4] = {};
    short8 afr[2][4][2];   // [eh][i][kb] — eh slabs persist across the K-tile
    short8 bfr[2][2];      // [j][kb]    — reused (B0 dead after phase 1)

    // prologue: tile 0 in consumption order A0, B0, A1, B1
    stage(0, 0); stage(0, 2); stage(0, 1); stage(0, 3);

    for (int t = 0; t < 16; ++t) {
        const int dbase = (t & 1) << 15;
#pragma unroll
        for (int ph = 0; ph < 4; ++ph) {
            // stage order per tile: A0,B0,A1,B1 -> kinds 0,2,1,3
            const int korder = (ph == 0) ? 0 : (ph == 1) ? 2 : (ph == 2) ? 1 : 3;
            if (t < 15) stage(t + 1, korder);
            __builtin_amdgcn_sched_barrier(0);
            if (t < 15) {
                asm volatile("s_waitcnt vmcnt(6)" ::: "memory");
            } else {
                if (ph == 0)      asm volatile("s_waitcnt vmcnt(4)" ::: "memory");
                else if (ph == 1) asm volatile("s_waitcnt vmcnt(2)" ::: "memory");
                else if (ph == 2) asm volatile("s_waitcnt vmcnt(0)" ::: "memory");
            }
            __builtin_amdgcn_s_barrier();
            __builtin_amdgcn_sched_barrier(0);

            const int eh = (ph == 1 || ph == 2) ? 1 : 0;
            const int sh = (ph >= 2) ? 1 : 0;

            if (ph == 0 || ph == 1) {   // new A slab
#pragma unroll
                for (int i = 0; i < 4; ++i) {
                    const int r = wr * 64 + i * 16 + lm;
#pragma unroll
                    for (int kb = 0; kb < 2; ++kb)
                        afr[eh][i][kb] = *reinterpret_cast<const short8*>(
                            &qkv_smem[dbase + eh * 8192 +
                                      (r * 8 + ((kb * 4 + g) ^ (r & 7))) * 8]);
                }
            }
            if (ph == 0 || ph == 2) {   // new B slab
#pragma unroll
                for (int j = 0; j < 2; ++j) {
                    const int r = wc * 32 + j * 16 + lm;
#pragma unroll
                    for (int kb = 0; kb < 2; ++kb)
                        bfr[j][kb] = *reinterpret_cast<const short8*>(
                            &qkv_smem[dbase + 16384 + sh * 8192 +
                                      (r * 8 + ((kb * 4 + g) ^ (r & 7))) * 8]);
                }
            }

            __builtin_amdgcn_s_setprio(1);
#pragma unroll
            for (int i = 0; i < 4; ++i)
#pragma unroll
                for (int j = 0; j < 2; ++j)
#pragma unroll
                    for (int kb = 0; kb < 2; ++kb)
                        acc[eh * 4 + i][sh * 2 + j] = __builtin_amdgcn_mfma_f32_16x16x32_bf16(
                            afr[eh][i][kb], bfr[j][kb], acc[eh * 4 + i][sh * 2 + j], 0, 0, 0);
            __builtin_amdgcn_s_setprio(0);

            __builtin_amdgcn_sched_barrier(0);
            __builtin_amdgcn_s_barrier();
            __builtin_amdgcn_sched_barrier(0);
        }
    }

    // ------------------------- epilogue -------------------------
    const int which = e0 >> 10;            // 0=Q,1=K,2=V (block-uniform)
    const int h0 = (e0 & 1023) >> 6;       // 4 heads per block
    const int bb = m0 >> 11, s0 = m0 & 2047;

    if (which < 2) {
        ushort_t* buf = (which == 0) ? Qb : Kb;
        const float qs = (which == 0) ? SCL : 1.0f;
#pragma unroll
        for (int half = 0; half < 2; ++half) {
            __syncthreads();
            if ((wc >> 1) == half) {
#pragma unroll
                for (int mf = 0; mf < 8; ++mf) {
                    const int ebase = wr * 128 + (mf >> 2) * 64 + (mf & 3) * 16 + g * 4;
                    const int d0 = ebase & 63;
#pragma unroll
                    for (int nf = 0; nf < 4; ++nf) {
                        const int slocg = wc * 64 + (nf >> 1) * 32 + (nf & 1) * 16 + lm;
                        const int sloc = slocg & 127;
                        float v[4] = {acc[mf][nf][0], acc[mf][nf][1], acc[mf][nf][2], acc[mf][nf][3]};
                        const int p = tpos[s0 + slocg];
                        const float4 c4 = *reinterpret_cast<const float4*>(&cosT[p * 64 + d0]);
                        const float4 s4 = *reinterpret_cast<const float4*>(&sinT[p * 64 + d0]);
                        const float r0 = (c4.x * v[0] + s4.x * v[1]) * qs;
                        const float r1 = (c4.y * v[1] + s4.y * v[0]) * qs;
                        const float r2 = (c4.z * v[2] + s4.z * v[3]) * qs;
                        const float r3 = (c4.w * v[3] + s4.w * v[2]) * qs;
                        uint2 pp;
                        pp.x = cvt_pk_bf16(r0, r1);
                        pp.y = cvt_pk_bf16(r2, r3);
                        *reinterpret_cast<uint2*>(&Es[sloc * 264 + ebase]) = pp;
                    }
                }
            }
            __syncthreads();
            // store 128 s x 256 e, coalesced 16B chunks
#pragma unroll
            for (int r = 0; r < 8; ++r) {
                const int idx = r * 512 + tid;
                const int sloc = idx >> 5, ec = (idx & 31) * 8;
                const int hh = ec >> 6, d = ec & 63;
                const short8 vv = *reinterpret_cast<const short8*>(&Es[sloc * 264 + ec]);
                ushort_t* dst = buf + (((size_t)bb * NH + h0 + hh) * SEQ +
                                       (s0 + half * 128 + sloc)) * DK + d;
                *reinterpret_cast<short8*>(dst) = vv;
            }
        }
    } else {
        // V: Es transposed [e][s-half], store [d][s] slabs to Vtb [B,H,DK,S]
#pragma unroll
        for (int half = 0; half < 2; ++half) {
            __syncthreads();
            if ((wc >> 1) == half) {
#pragma unroll
                for (int mf = 0; mf < 8; ++mf) {
                    const int ebase = wr * 128 + (mf >> 2) * 64 + (mf & 3) * 16 + g * 4;
#pragma unroll
                    for (int nf = 0; nf < 4; ++nf) {
                        const int slocg = wc * 64 + (nf >> 1) * 32 + (nf & 1) * 16 + lm;
                        const int sloc = slocg & 127;
                        Es[(ebase + 0) * 136 + sloc] = f2bf(acc[mf][nf][0]);
                        Es[(ebase + 1) * 136 + sloc] = f2bf(acc[mf][nf][1]);
                        Es[(ebase + 2) * 136 + sloc] = f2bf(acc[mf][nf][2]);
                        Es[(ebase + 3) * 136 + sloc] = f2bf(acc[mf][nf][3]);
                    }
                }
            }
            __syncthreads();
#pragma unroll
            for (int r = 0; r < 8; ++r) {
                const int idx = r * 512 + tid;
                const int erow = idx >> 4, sc8 = (idx & 15) * 8;
                const int hh = erow >> 6, d = erow & 63;
                const short8 vv = *reinterpret_cast<const short8*>(&Es[erow * 136 + sc8]);
                ushort_t* dst = Vtb + (((size_t)bb * NH + h0 + hh) * DK + d) * SEQ +
                                s0 + half * 128 + sc8;
                *reinterpret_cast<short8*>(dst) = vv;
            }
        }
    }
}

// ---------------------------------------------------------------------------
// Kernel 2: flash attention — merged q-tiles, fixed-max softmax (exp2 fold,
// scale pre-folded into Q), in-register P transpose (cvt_pk + permlane),
// row-sum via ones-MFMA, single-barrier double-buffered K/V staging.
// (unchanged — verified)
// ---------------------------------------------------------------------------
#define ATTN_STEP(QF0, QF1, QROW, LACC, OACC, DIAG, C0)                           \
    {                                                                             \
        v4f sacc[4] = {};                                                         \
        _Pragma("unroll")                                                         \
        for (int nf = 0; nf < 4; ++nf) {                                          \
            sacc[nf] = __builtin_amdgcn_mfma_f32_16x16x32_bf16(kf[nf][0], QF0, sacc[nf], 0, 0, 0); \
            sacc[nf] = __builtin_amdgcn_mfma_f32_16x16x32_bf16(kf[nf][1], QF1, sacc[nf], 0, 0, 0); \
        }                                                                         \
        if (DIAG) {                                                               \
            _Pragma("unroll")                                                     \
            for (int nf = 0; nf < 4; ++nf)                                        \
                _Pragma("unroll")                                                 \
                for (int reg = 0; reg < 4; ++reg) {                               \
                    const int kv = (C0) + nf * 16 + g * 4 + reg;                  \
                    if (kv > (QROW)) sacc[nf][reg] = NEG_BIG;                     \
                }                                                                 \
        }                                                                         \
        unsigned pk0[8];                                                          \
        _Pragma("unroll")                                                         \
        for (int nf = 0; nf < 4; ++nf) {                                          \
            pk0[nf * 2]     = cvt_pk_bf16(exp2f(sacc[nf][0]), exp2f(sacc[nf][1])); \
            pk0[nf * 2 + 1] = cvt_pk_bf16(exp2f(sacc[nf][2]), exp2f(sacc[nf][3])); \
        }                                                                         \
        _Pragma("unroll")                                                         \
        for (int kc = 0; kc < 2; ++kc) {                                          \
            unsigned x0 = pk0[kc * 4 + 0], y0 = pk0[kc * 4 + 2];                  \
            unsigned x1 = pk0[kc * 4 + 1], y1 = pk0[kc * 4 + 3];                  \
            permlane32_swap(x0, y0); permlane16_swap(x0, y0);                     \
            permlane32_swap(x1, y1); permlane16_swap(x1, y1);                     \
            union { unsigned u[4]; short8 s; } pu;                                \
            pu.u[0] = x0; pu.u[1] = x1; pu.u[2] = y0; pu.u[3] = y1;               \
            const short8 pf = pu.s;                                               \
            LACC = __builtin_amdgcn_mfma_f32_16x16x32_bf16(ones8, pf, LACC, 0, 0, 0); \
            _Pragma("unroll")                                                     \
            for (int df = 0; df < 4; ++df)                                        \
                OACC[df] = __builtin_amdgcn_mfma_f32_16x16x32_bf16(vf[df][kc], pf, OACC[df], 0, 0, 0); \
        }                                                                         \
    }

__global__ __launch_bounds__(256, 2) void attn_mfma_kernel(
    const ushort_t* __restrict__ Qb, const ushort_t* __restrict__ Kb,
    const ushort_t* __restrict__ Vtb, ushort_t* __restrict__ attb)
{
    __shared__ ushort_t Ks[2][64][72];   // [buf][kv][d]
    __shared__ ushort_t Vs[2][64][72];   // [buf][d][kv]  (V^T)

    const int tid = threadIdx.x;
    const int w = tid >> 6, lane = tid & 63;
    const int lm = lane & 15, g = lane >> 4, lk8 = g * 8;

    const int u = blockIdx.x;                     // 0..15
    const int h = blockIdx.y, b = blockIdx.z;
    const size_t ho = ((size_t)b * NH + h) * SEQ * DK;
    const ushort_t* Qh = Qb + ho;
    const ushort_t* Kh = Kb + ho;
    const ushort_t* Vth = Vtb + ho;               // [DK][SEQ]

    const int rr0 = tid >> 3, cc80 = (tid & 7) * 8;
    const int rr1 = (tid + 256) >> 3, cc81 = ((tid + 256) & 7) * 8;

    const int it1 = u, it2 = 31 - u;              // it1 <= it2 (u < 16)
    const int qrowA = it1 * 64 + w * 16 + lm;
    const int qrowB = it2 * 64 + w * 16 + lm;

    const short8 qa0 = *reinterpret_cast<const short8*>(&Qh[(size_t)qrowA * DK + lk8]);
    const short8 qa1 = *reinterpret_cast<const short8*>(&Qh[(size_t)qrowA * DK + 32 + lk8]);
    const short8 qb0 = *reinterpret_cast<const short8*>(&Qh[(size_t)qrowB * DK + lk8]);
    const short8 qb1 = *reinterpret_cast<const short8*>(&Qh[(size_t)qrowB * DK + 32 + lk8]);

    const short8 ones8 = {16256, 16256, 16256, 16256, 16256, 16256, 16256, 16256}; // bf16 1.0

    v4f laccA = {}, laccB = {};
    v4f OA[4] = {}, OB[4] = {};

    // preload jt=0
    short8 kreg[2], vreg[2];
    kreg[0] = *reinterpret_cast<const short8*>(&Kh[(size_t)rr0 * DK + cc80]);
    kreg[1] = *reinterpret_cast<const short8*>(&Kh[(size_t)rr1 * DK + cc81]);
    vreg[0] = *reinterpret_cast<const short8*>(&Vth[(size_t)rr0 * SEQ + cc80]);
    vreg[1] = *reinterpret_cast<const short8*>(&Vth[(size_t)rr1 * SEQ + cc81]);

    for (int jt = 0; jt <= it2; ++jt) {
        const int c0 = jt * 64;
        const int bufi = jt & 1;
        ushort_t (*Ksb)[72] = Ks[bufi];
        ushort_t (*Vsb)[72] = Vs[bufi];

        *reinterpret_cast<short8*>(&Ksb[rr0][cc80]) = kreg[0];
        *reinterpret_cast<short8*>(&Ksb[rr1][cc81]) = kreg[1];
        *reinterpret_cast<short8*>(&Vsb[rr0][cc80]) = vreg[0];
        *reinterpret_cast<short8*>(&Vsb[rr1][cc81]) = vreg[1];

        if (jt < it2) {    // prefetch next tile; latency hides behind compute
            const int c0n = c0 + 64;
            kreg[0] = *reinterpret_cast<const short8*>(&Kh[(size_t)(c0n + rr0) * DK + cc80]);
            kreg[1] = *reinterpret_cast<const short8*>(&Kh[(size_t)(c0n + rr1) * DK + cc81]);
            vreg[0] = *reinterpret_cast<const short8*>(&Vth[(size_t)rr0 * SEQ + c0n + cc80]);
            vreg[1] = *reinterpret_cast<const short8*>(&Vth[(size_t)rr1 * SEQ + c0n + cc81]);
        }

        __syncthreads();   // staged (single barrier per iter; dbuf handles WAR)

        // shared K/V fragment loads (both q-tiles consume the same tile)
        short8 kf[4][2], vf[4][2];
#pragma unroll
        for (int nf = 0; nf < 4; ++nf) {
            kf[nf][0] = *reinterpret_cast<const short8*>(&Ksb[nf * 16 + lm][lk8]);
            kf[nf][1] = *reinterpret_cast<const short8*>(&Ksb[nf * 16 + lm][32 + lk8]);
        }
#pragma unroll
        for (int df = 0; df < 4; ++df) {
            vf[df][0] = *reinterpret_cast<const short8*>(&Vsb[df * 16 + lm][lk8]);
            vf[df][1] = *reinterpret_cast<const short8*>(&Vsb[df * 16 + lm][32 + lk8]);
        }

        // tile B (always active; masks on its own diagonal)
        ATTN_STEP(qb0, qb1, qrowB, laccB, OB, (jt == it2), c0)
        // tile A (active while jt <= it1)
        if (jt <= it1) {
            ATTN_STEP(qa0, qa1, qrowA, laccA, OA, (jt == it1), c0)
        }
    }

    // epilogue: lacc holds the FULL row sum in every lane
    {
        const float inv = 1.0f / laccA[0];
#pragma unroll
        for (int df = 0; df < 4; ++df) {
            uint2 st;
            st.x = cvt_pk_bf16(OA[df][0] * inv, OA[df][1] * inv);
            st.y = cvt_pk_bf16(OA[df][2] * inv, OA[df][3] * inv);
            *reinterpret_cast<uint2*>(
                &attb[((size_t)b * SEQ + qrowA) * DMODEL + h * DK + df * 16 + g * 4]) = st;
        }
    }
    {
        const float inv = 1.0f / laccB[0];
#pragma unroll
        for (int df = 0; df < 4; ++df) {
            uint2 st;
            st.x = cvt_pk_bf16(OB[df][0] * inv, OB[df][1] * inv);
            st.y = cvt_pk_bf16(OB[df][2] * inv, OB[df][3] * inv);
            *reinterpret_cast<uint2*>(
                &attb[((size_t)b * SEQ + qrowB) * DMODEL + h * DK + df * 16 + g * 4]) = st;
        }
    }
}

// ---------------------------------------------------------------------------
// Kernel 3: output projection — dbuf counted-vmcnt structure (unchanged).
// ---------------------------------------------------------------------------
#define OUT_STAGE(bofs, k0s)                                                   \
    _Pragma("unroll")                                                          \
    for (int j = 0; j < 4; ++j)                                                \
        gl_lds16(&attb[(size_t)(m0 + srow[j]) * DMODEL + (k0s) + skc[j]],      \
                 &smem[(bofs) + (tid + 256 * j) * 8]);                         \
    _Pragma("unroll")                                                          \
    for (int j = 4; j < 8; ++j)                                                \
        gl_lds16(&Wob[(size_t)(n0 + srow[j]) * DMODEL + (k0s) + skc[j]],       \
                 &smem[(bofs) + (tid + 256 * j) * 8]);

__global__ __launch_bounds__(256) void out_mfma_kernel(
    const ushort_t* __restrict__ attb,  // [4096,1024] bf16
    const ushort_t* __restrict__ Wob,   // [1024,1024] bf16
    float* __restrict__ out)            // [4096,1024] fp32
{
    __shared__ ushort_t smem[32768];    // 2 x 32KB staging buffers

    const int tid = threadIdx.x;
    const int w = tid >> 6, lane = tid & 63;
    const int lm = lane & 15, g = lane >> 4;
    const int wm = (w >> 1) * 64, wn = (w & 1) * 64;

    // T1: bijective XCD-chunked swizzle (256 = 8 * 32)
    const int lid = blockIdx.y * 8 + blockIdx.x;
    const int swz = (lid & 7) * 32 + (lid >> 3);
    const int m0 = (swz >> 3) * 128, n0 = (swz & 7) * 128;

    int srow[8], skc[8];
#pragma unroll
    for (int j = 0; j < 8; ++j) {
        const int c = tid + 256 * j;
        const int cm = c & 1023;
        const int row = cm >> 3, pp = cm & 7;
        srow[j] = row;
        skc[j] = (pp ^ (row & 7)) * 8;
    }

    v4f acc[4][4] = {};

    OUT_STAGE(0, 0);

    for (int t = 0; t < 16; ++t) {
        const int bofs = (t & 1) << 14;
        if (t < 15) {
            const int nofs = ((t + 1) & 1) << 14;
            OUT_STAGE(nofs, (t + 1) * 64);
            __builtin_amdgcn_sched_barrier(0);
            asm volatile("s_waitcnt vmcnt(8)" ::: "memory");
        } else {
            __builtin_amdgcn_sched_barrier(0);
            asm volatile("s_waitcnt vmcnt(0)" ::: "memory");
        }
        __builtin_amdgcn_s_barrier();
        __builtin_amdgcn_sched_barrier(0);

        __builtin_amdgcn_s_setprio(1);
#pragma unroll
        for (int kb = 0; kb < 2; ++kb) {
            short8 af[4], bfr[4];
#pragma unroll
            for (int mf = 0; mf < 4; ++mf) {
                const int r = wm + mf * 16 + lm;
                af[mf] = *reinterpret_cast<const short8*>(
                    &smem[bofs + (r * 8 + ((kb * 4 + g) ^ (r & 7))) * 8]);
            }
#pragma unroll
            for (int nf = 0; nf < 4; ++nf) {
                const int r = wn + nf * 16 + lm;
                bfr[nf] = *reinterpret_cast<const short8*>(
                    &smem[bofs + 8192 + (r * 8 + ((kb * 4 + g) ^ (r & 7))) * 8]);
            }
#pragma unroll
            for (int mf = 0; mf < 4; ++mf)
#pragma unroll
                for (int nf = 0; nf < 4; ++nf)
                    acc[mf][nf] = __builtin_amdgcn_mfma_f32_16x16x32_bf16(af[mf], bfr[nf], acc[mf][nf], 0, 0, 0);
        }
        __builtin_amdgcn_s_setprio(0);

        __builtin_amdgcn_sched_barrier(0);
        __builtin_amdgcn_s_barrier();
        __builtin_amdgcn_sched_barrier(0);
    }

#pragma unroll
    for (int mf = 0; mf < 4; ++mf)
#pragma unroll
        for (int reg = 0; reg < 4; ++reg) {
            const int m = m0 + wm + mf * 16 + g * 4 + reg;
#pragma unroll
            for (int nf = 0; nf < 4; ++nf) {
                const int n = n0 + wn + nf * 16 + lm;
                out[(size_t)m * DMODEL + n] = acc[mf][nf][reg];
            }
        }
}

// ---------------------------------------------------------------------------
extern "C" void kernel_launch(void* const* d_in, const int* in_sizes, int n_in,
                              void* d_out, int out_size, void* d_ws, size_t ws_size,
                              hipStream_t stream) {
    (void)in_sizes; (void)n_in; (void)out_size; (void)ws_size;

    const float* x    = (const float*)d_in[0];
    const float* Wa   = (const float*)d_in[1];
    const float* Wo   = (const float*)d_in[2];
    const float* rope = (const float*)d_in[3];
    const int*   tp   = (const int*)d_in[4];
    float* out = (float*)d_out;

    char* ws = (char*)d_ws;
    ushort_t* xb   = (ushort_t*)(ws);                       // 8 MB
    ushort_t* Wab  = (ushort_t*)(ws + (8u << 20));          // 6 MB
    ushort_t* Wob  = (ushort_t*)(ws + (14u << 20));         // 2 MB
    float*    cosT = (float*)   (ws + (16u << 20));         // 0.5 MB
    float*    sinT = (float*)   (ws + (16u << 20) + (512u << 10));
    ushort_t* Qb   = (ushort_t*)(ws + (17u << 20));         // 8 MB
    ushort_t* Kb   = (ushort_t*)(ws + (25u << 20));         // 8 MB
    ushort_t* Vtb  = (ushort_t*)(ws + (33u << 20));         // 8 MB
    ushort_t* attb = (ushort_t*)(ws + (41u << 20));         // 8 MB

    dim3 blk(256);
    prep_kernel<<<dim3(8704), blk, 0, stream>>>(x, Wa, Wo, rope, xb, Wab, Wob, cosT, sinT);

    qkv_mfma_kernel<<<dim3(NQKV / 256, M_ROWS / 256), dim3(512), 0, stream>>>(
        xb, Wab, cosT, sinT, tp, Qb, Kb, Vtb);
    attn_mfma_kernel<<<dim3(16, NH, B_SZ), blk, 0, stream>>>(Qb, Kb, Vtb, attb);
    out_mfma_kernel<<<dim3(DMODEL / 128, M_ROWS / 128), blk, 0, stream>>>(attb, Wob, out);
}